// Round 12
// baseline (667.777 us; speedup 1.0000x reference)
//
#include <hip/hip_runtime.h>
#include <hip/hip_bf16.h>
#include <cstdint>
#include <cstddef>

#define BATCH  256
#define HID    1024
#define TSTEPS 128
#define NBLK   256   // 8 pairs x 32 jblk; block serves mgrps {pair, pair+8}
#define NTHR   512   // 8 waves = 2 ngrp (3 n-tiles) x 4 kh (8 c-steps)

typedef __attribute__((ext_vector_type(8))) short bf16x8;
typedef __attribute__((ext_vector_type(4))) float f32x4;

#define MFMA(a, b, c) __builtin_amdgcn_mfma_f32_16x16x32_bf16((a), (b), (c), 0, 0, 0)

// fast gates: native exp2/rcp (error ~1e-6; absmax margin ~5x)
__device__ inline float fsigmoid(float x) {
    return __builtin_amdgcn_rcpf(1.f + __builtin_amdgcn_exp2f(-1.44269504f * x));
}
__device__ inline float ftanh(float x) {
    return 1.f - 2.f * __builtin_amdgcn_rcpf(1.f + __builtin_amdgcn_exp2f(2.88539008f * x));
}

// ---------------------------------------------------------------------------
// prep: pack w_hh (bf16) frag-major (r8-proven layout):
//   frag g = ((jb*6 + n)*32 + c)*64 + l ; wrow = gate*1024+jb*32+ch*16+(l&15);
//   k = c*32 + (l>>4)*8   (gate=n>>1, ch=n&1)
// h0 -> bf16; flag array zeroed.
// ---------------------------------------------------------------------------
__global__ void prep_kernel(const float* __restrict__ vectors,
                            const float* __restrict__ w_hh,
                            __hip_bfloat16* __restrict__ h0,
                            __hip_bfloat16* __restrict__ w2,
                            unsigned* __restrict__ bar)
{
    const long long stride = (long long)gridDim.x * blockDim.x;
    const long long idx = (long long)blockIdx.x * blockDim.x + threadIdx.x;

    const long long NG = 32LL * 6 * 32 * 64;
    for (long long g = idx; g < NG; g += stride) {
        const int l  = (int)(g & 63);
        const int c  = (int)((g >> 6) & 31);
        const int nj = (int)(g >> 11);
        const int n  = nj % 6;
        const int jb = nj / 6;
        const int gate = n >> 1, ch = n & 1;
        const int wrow = gate * HID + jb * 32 + ch * 16 + (l & 15);
        const int k    = c * 32 + (l >> 4) * 8;
        const float* src = w_hh + (size_t)wrow * HID + k;
        alignas(16) __hip_bfloat16 v[8];
        #pragma unroll
        for (int e = 0; e < 8; ++e) v[e] = __float2bfloat16(src[e]);
        *(bf16x8*)(w2 + g * 8) = *(const bf16x8*)v;
    }

    const long long NH = (long long)BATCH * HID;
    for (long long i = idx; i < NH; i += stride)
        h0[i] = __float2bfloat16(vectors[i]);

    for (long long i = idx; i < 1024; i += stride) bar[i] = 0u;
}

// ---------------------------------------------------------------------------
// Persistent GRU, dual-pipeline blocks. 256 blocks = 8 pairs x 32 jblk;
// launch config IDENTICAL to r8 (512 thr, bounds(512,2), 1 block/CU) -> the
// cooperative launch is valid unconditionally (r10/r11 failed on occupancy).
// Each block interleaves TWO independent mgrps (16 rows each: pair, pair+8):
// while pipeline p computes GEMM+epilogue, the prefetch for the other
// pipeline (poll flags + issue A-tile loads, no waitcnt) is in flight --
// IC RTT and peer skew hide under compute. Weights (shared by both mgrps)
// live in registers. y computed locally via masked MFMA; jblk==0 writes out.
// Cross-block protocol per half identical to r8.
// ---------------------------------------------------------------------------
__global__ __launch_bounds__(NTHR, 2)
void gru_persistent(const float* __restrict__ vectors,
                    const float* __restrict__ w_ih,
                    const float* __restrict__ b_ih,
                    const float* __restrict__ b_hh,
                    const float* __restrict__ w_ffn,
                    const float* __restrict__ b_ffn,
                    const float* __restrict__ first_input,
                    __hip_bfloat16* __restrict__ h_a,
                    __hip_bfloat16* __restrict__ h_b,
                    const __hip_bfloat16* __restrict__ w2,
                    unsigned* __restrict__ bar,
                    float* __restrict__ out)
{
    __shared__ alignas(16) unsigned char ldsA[2][32768];   // per-pipeline h tile
    __shared__ float ghp[4][3][16][36];                    // gh K-partials (reused)
    __shared__ float ghy[4][16];                           // y K-partials (reused)
    __shared__ alignas(16) __hip_bfloat16 hstage[512];
    __shared__ __hip_bfloat16 wffn_lds[1024];

    const int blk  = blockIdx.x;
    const int jblk = blk & 31;
    const int pair = blk >> 5;                 // 0..7
    const int j_base = jblk * 32;
    const int tid  = threadIdx.x;
    const int lane = tid & 63, wv = tid >> 6;
    const int ngrp = wv & 1, kh = wv >> 1;
    const int l15  = lane & 15, kg = lane >> 4;

    // epilogue constants (1 elem/thread per pipeline)
    const int eb = tid >> 5, ejc = tid & 31;
    const int ej = j_base + ejc;
    float wih_[3];
    #pragma unroll
    for (int g = 0; g < 3; ++g) wih_[g] = w_ih[g * HID + ej];
    const float bsum0 = b_ih[ej] + b_hh[ej];
    const float bsum1 = b_ih[HID + ej] + b_hh[HID + ej];
    const float bin_  = b_ih[2 * HID + ej];
    const float bhn_  = b_hh[2 * HID + ej];
    float hreg[2];
    hreg[0] = vectors[(size_t)(pair * 16 + eb) * HID + ej];
    hreg[1] = vectors[(size_t)((pair + 8) * 16 + eb) * HID + ej];
    const float x0  = first_input[0];
    const float bff = b_ffn[0];

    for (int i = tid; i < 1024; i += NTHR)
        wffn_lds[i] = __float2bfloat16(w_ffn[i]);

    // B weights -> registers (24 frags = 96 VGPRs), shared by both pipelines
    bf16x8 Breg[3][8];
    {
        const bf16x8* w2f = (const bf16x8*)w2;
        #pragma unroll
        for (int nn = 0; nn < 3; ++nn)
            #pragma unroll
            for (int cc = 0; cc < 8; ++cc)
                Breg[nn][cc] =
                    w2f[((size_t)(jblk * 6 + ngrp * 3 + nn) * 32 + kh * 8 + cc) * 64 + lane];
    }

    const int swz = (l15 & 7) << 4;
    const int rb0 = l15 * 2048;
    const bf16x8 zb = {0, 0, 0, 0, 0, 0, 0, 0};

    // prologue: region0 <- h_0[mgA]
    {
        const uint4* src = (const uint4*)(h_a + (size_t)pair * 16 * HID);
        uint4 tp[4];
        #pragma unroll
        for (int it = 0; it < 4; ++it) {
            asm volatile("global_load_dwordx4 %0, %1, off sc0 sc1"
                         : "=v"(tp[it]) : "v"(src + tid + it * NTHR) : "memory");
        }
        asm volatile("s_waitcnt vmcnt(0)" ::: "memory");
        #pragma unroll
        for (int it = 0; it < 4; ++it) {
            int g = tid + it * NTHR;
            int row = g >> 7, k16 = g & 127;
            *(uint4*)(&ldsA[0][0] + row * 2048 + ((k16 << 4) ^ ((row & 7) << 4))) = tp[it];
        }
    }
    __syncthreads();

    for (int t = 0; t <= TSTEPS; ++t) {
        #pragma unroll
        for (int ph = 0; ph < 2; ++ph) {
            const int mg = ph ? (pair + 8) : pair;
            const int mb = mg * 16;
            const int nmg = ph ? pair : (pair + 8);   // next half's mgrp
            const int nt  = ph ? t + 1 : t;           // next half's step
            const bool haveNext = !(ph == 1 && t == TSTEPS);

            // ---- poll next flags (per-wave) + issue next A-loads (pending) ----
            uint4 tp[4];
            if (haveNext) {
                if (lane < 32) {
                    const unsigned* fp = &bar[nmg * 32 + lane];
                    while (__hip_atomic_load(fp, __ATOMIC_RELAXED,
                                             __HIP_MEMORY_SCOPE_SYSTEM) < (unsigned)nt)
                        __builtin_amdgcn_s_sleep(1);
                }
                const __hip_bfloat16* hsrc = (nt & 1) ? h_b : h_a;
                const uint4* src = (const uint4*)(hsrc + (size_t)nmg * 16 * HID);
                #pragma unroll
                for (int it = 0; it < 4; ++it) {
                    asm volatile("global_load_dwordx4 %0, %1, off sc0 sc1"
                                 : "=v"(tp[it]) : "v"(src + tid + it * NTHR) : "memory");
                }
            }

            if (t < TSTEPS) {
                // ---- GEMM (B from regs) + local y-MFMA ----
                f32x4 acc0 = {0.f,0.f,0.f,0.f}, acc1 = acc0, acc2 = acc0, accy = acc0;
                const unsigned char* base = &ldsA[ph][0];
                #pragma unroll
                for (int cc = 0; cc < 8; ++cc) {
                    const int c = (kh << 3) + cc;
                    const int colb = ((c << 6) | (kg << 4)) ^ swz;
                    bf16x8 a0 = *(const bf16x8*)(base + rb0 + colb);
                    acc0 = MFMA(a0, Breg[0][cc], acc0);
                    acc1 = MFMA(a0, Breg[1][cc], acc1);
                    acc2 = MFMA(a0, Breg[2][cc], acc2);
                    if (ngrp == 0 && t > 0) {
                        bf16x8 wfv = *(const bf16x8*)(wffn_lds + c * 32 + kg * 8);
                        bf16x8 wb = (l15 == 0) ? wfv : zb;
                        accy = MFMA(a0, wb, accy);
                    }
                }
                {
                    const int n0 = ngrp * 3;
                    #pragma unroll
                    for (int r = 0; r < 4; ++r) {
                        const int rw = kg * 4 + r;
                        ghp[kh][(n0    ) >> 1][rw][(((n0    ) & 1) << 4) + l15] = acc0[r];
                        ghp[kh][(n0 + 1) >> 1][rw][(((n0 + 1) & 1) << 4) + l15] = acc1[r];
                        ghp[kh][(n0 + 2) >> 1][rw][(((n0 + 2) & 1) << 4) + l15] = acc2[r];
                    }
                    if (ngrp == 0 && t > 0 && l15 == 0) {
                        #pragma unroll
                        for (int r = 0; r < 4; ++r) ghy[kh][kg * 4 + r] = accy[r];
                    }
                }
                __syncthreads();

                // ---- epilogue (1 elem/thread) ----
                {
                    const float x = (t == 0) ? x0
                        : (ghy[0][eb] + ghy[1][eb] + ghy[2][eb] + ghy[3][eb] + bff);
                    float ghr = bsum0, ghz = bsum1, ghn = bhn_;
                    #pragma unroll
                    for (int p = 0; p < 4; ++p) {
                        ghr += ghp[p][0][eb][ejc];
                        ghz += ghp[p][1][eb][ejc];
                        ghn += ghp[p][2][eb][ejc];
                    }
                    const float rg = fsigmoid(fmaf(x, wih_[0], ghr));
                    const float zg = fsigmoid(fmaf(x, wih_[1], ghz));
                    const float gin = fmaf(x, wih_[2], bin_);
                    const float ng = ftanh(fmaf(rg, ghn, gin));
                    const float hnew = (1.f - zg) * ng + zg * hreg[ph];
                    hreg[ph] = hnew;
                    hstage[eb * 32 + ejc] = __float2bfloat16(hnew);
                    if (t > 0 && jblk == 0 && ejc == 0)
                        out[(size_t)(mb + eb) * TSTEPS + (t - 1)] = x;
                }
                __syncthreads();

                // ---- h_{t+1} stores (128 x 8B, system scope) ----
                __hip_bfloat16* hnxt = (t & 1) ? h_a : h_b;
                if (tid < 128) {
                    const int b = tid >> 3, off = tid & 7;
                    unsigned long long v =
                        *(const unsigned long long*)((const char*)hstage + b * 64 + off * 8);
                    __hip_atomic_store(
                        (unsigned long long*)(hnxt + (size_t)(mb + b) * HID + j_base + off * 4),
                        v, __ATOMIC_RELAXED, __HIP_MEMORY_SCOPE_SYSTEM);
                }
                __syncthreads();   // drains vmcnt: h stores + pending tp loads done
                if (tid == 0)
                    __hip_atomic_store(&bar[mg * 32 + jblk], (unsigned)(t + 1),
                                       __ATOMIC_RELAXED, __HIP_MEMORY_SCOPE_SYSTEM);
                if (haveNext) {
                    #pragma unroll
                    for (int it = 0; it < 4; ++it) {
                        int g = tid + it * NTHR;
                        int row = g >> 7, k16 = g & 127;
                        *(uint4*)(&ldsA[ph ^ 1][0] + row * 2048 +
                                  ((k16 << 4) ^ ((row & 7) << 4))) = tp[it];
                    }
                }
                __syncthreads();   // next half's region ready
            } else {
                // ---- t == TSTEPS: final y for this pipeline ----
                if (ngrp == 0) {
                    f32x4 accy = {0.f,0.f,0.f,0.f};
                    const unsigned char* base = &ldsA[ph][0];
                    #pragma unroll
                    for (int cc = 0; cc < 8; ++cc) {
                        const int c = (kh << 3) + cc;
                        const int colb = ((c << 6) | (kg << 4)) ^ swz;
                        bf16x8 a0 = *(const bf16x8*)(base + rb0 + colb);
                        bf16x8 wfv = *(const bf16x8*)(wffn_lds + c * 32 + kg * 8);
                        bf16x8 wb = (l15 == 0) ? wfv : zb;
                        accy = MFMA(a0, wb, accy);
                    }
                    if (l15 == 0) {
                        #pragma unroll
                        for (int r = 0; r < 4; ++r) ghy[kh][kg * 4 + r] = accy[r];
                    }
                }
                __syncthreads();
                if (jblk == 0 && tid < 16)
                    out[(size_t)(mb + tid) * TSTEPS + (TSTEPS - 1)] =
                        ghy[0][tid] + ghy[1][tid] + ghy[2][tid] + ghy[3][tid] + bff;
                __syncthreads();   // ghy consumed; vmcnt drained (tp loads done)
                if (haveNext) {
                    #pragma unroll
                    for (int it = 0; it < 4; ++it) {
                        int g = tid + it * NTHR;
                        int row = g >> 7, k16 = g & 127;
                        *(uint4*)(&ldsA[ph ^ 1][0] + row * 2048 +
                                  ((k16 << 4) ^ ((row & 7) << 4))) = tp[it];
                    }
                }
                __syncthreads();
            }
        }
    }
}

extern "C" void kernel_launch(void* const* d_in, const int* in_sizes, int n_in,
                              void* d_out, int out_size, void* d_ws, size_t ws_size,
                              hipStream_t stream)
{
    const float* vectors     = (const float*)d_in[0];
    const float* w_ih        = (const float*)d_in[1];
    const float* w_hh        = (const float*)d_in[2];
    const float* b_ih        = (const float*)d_in[3];
    const float* b_hh        = (const float*)d_in[4];
    const float* w_ffn       = (const float*)d_in[5];
    const float* b_ffn       = (const float*)d_in[6];
    const float* first_input = (const float*)d_in[7];
    float* out = (float*)d_out;

    // workspace carve (~7.4 MB)
    char* p = (char*)d_ws;
    __hip_bfloat16* h_a = (__hip_bfloat16*)p;  p += (size_t)BATCH * HID * 2;
    __hip_bfloat16* h_b = (__hip_bfloat16*)p;  p += (size_t)BATCH * HID * 2;
    __hip_bfloat16* w2  = (__hip_bfloat16*)p;  p += 32LL * 6 * 32 * 64 * 8 * 2;
    unsigned* bar = (unsigned*)p;              p += 1024 * 4;   // flags[512]

    prep_kernel<<<1024, 256, 0, stream>>>(vectors, w_hh, h_a, w2, bar);

    void* args[] = {
        (void*)&vectors, (void*)&w_ih, (void*)&b_ih, (void*)&b_hh,
        (void*)&w_ffn, (void*)&b_ffn, (void*)&first_input,
        (void*)&h_a, (void*)&h_b, (void*)&w2, (void*)&bar, (void*)&out
    };
    hipError_t err = hipLaunchCooperativeKernel((const void*)gru_persistent,
                               dim3(NBLK), dim3(NTHR), args, 0, stream);
    (void)err;
}